// Round 1
// baseline (507.146 us; speedup 1.0000x reference)
//
#include <hip/hip_runtime.h>
#include <hip/hip_bf16.h>

// Problem constants: B=65536, A=8, E=128, K=2E=256
typedef __attribute__((ext_vector_type(8))) short short8;   // 8 bf16 = 4 VGPRs
typedef __attribute__((ext_vector_type(4))) float floatx4;  // MFMA accumulator

__device__ inline short f2bf(float f) {
  // round-to-nearest-even fp32 -> bf16 (no NaN handling needed: inputs are finite)
  unsigned u = __builtin_bit_cast(unsigned, f);
  unsigned r = u + 0x7fffu + ((u >> 16) & 1u);
  return (short)(r >> 16);
}

__device__ inline short8 cvt8(float4 a, float4 b) {
  short8 r;
  r[0] = f2bf(a.x); r[1] = f2bf(a.y); r[2] = f2bf(a.z); r[3] = f2bf(a.w);
  r[4] = f2bf(b.x); r[5] = f2bf(b.y); r[6] = f2bf(b.z); r[7] = f2bf(b.w);
  return r;
}

// ---------------------------------------------------------------------------
// Phase 1: fold W_agg into proj.
//   Mt[a][j][k] = sum_i W_agg[i][k] * proj[a][i][j]   (bf16, transposed so the
//                 GEMM's B-fragment reads are k-contiguous)
//   bias2[a][j] = sum_i b_agg[i] * proj[a][i][j]       (fp32)
// grid = A*E = 1024 blocks, 256 threads (one thread per k).
// ---------------------------------------------------------------------------
__global__ __launch_bounds__(256) void prep_M(
    const float* __restrict__ W, const float* __restrict__ proj,
    const float* __restrict__ bvec, short* __restrict__ Mt,
    float* __restrict__ bias2) {
  int blk = blockIdx.x;
  int a = blk >> 7, j = blk & 127;
  int k = threadIdx.x;  // 0..255
  const float* pj = proj + a * 16384 + j;  // proj[a][i][j], stride 128
  float acc = 0.f;
#pragma unroll 4
  for (int i = 0; i < 128; ++i)
    acc += W[i * 256 + k] * pj[i * 128];  // W coalesced over k, proj broadcast
  Mt[a * 32768 + j * 256 + k] = f2bf(acc);
  if (k == 0) {
    float b = 0.f;
    for (int i = 0; i < 128; ++i) b += bvec[i] * pj[i * 128];
    bias2[a * 128 + j] = b;
  }
}

// ---------------------------------------------------------------------------
// Phase 2: out[b,a,j] = [img[b,:] | edge[b,a,:]] @ Mt[a]^T + bias2[a,:]
// Per-block: 128 rows (b) x 128 cols (j), K=256 in 8 steps of BK=32.
// 256 threads = 4 waves in a 2x2 grid, each wave 4x4 tiles of 16x16x32 MFMA.
// LDS rows padded to 40 bf16 (80 B) -> bank-uniform b128 access.
// ---------------------------------------------------------------------------
__global__ __launch_bounds__(256) void gemm_main(
    const float* __restrict__ img, const float* __restrict__ edge,
    const short* __restrict__ Mt, const float* __restrict__ bias2,
    float* __restrict__ out) {
  constexpr int LDA = 40;
  __shared__ short As[128 * LDA];  // X tile   [m=128][k=32] (+pad) 20 KB
  __shared__ short Bs[128 * LDA];  // M_a tile [n=128][k=32] (+pad) 20 KB

  const int tid = threadIdx.x;
  const int a = blockIdx.x & 7;          // attribute type -> spreads over XCDs
  const int b0 = (blockIdx.x >> 3) << 7; // batch-tile base
  const int wave = tid >> 6, lane = tid & 63;
  const int quad = lane >> 4, l16 = lane & 15;
  const int wm = wave & 1, wn = wave >> 1;

  floatx4 acc[4][4] = {};
  const short* Mta = Mt + a * 32768;

  for (int ks = 0; ks < 8; ++ks) {
    // --- stage A (fp32 -> bf16 in regs): 128x32 floats, 16 floats/thread ---
#pragma unroll
    for (int i = 0; i < 2; ++i) {
      int slot = tid + i * 256;          // 0..511, 8 floats each
      int row = slot >> 2, c8 = slot & 3;
      const float* src;
      if (ks < 4)  // k < 128: img half of the concat
        src = img + (size_t)(b0 + row) * 128 + ks * 32 + c8 * 8;
      else         // k >= 128: edge half
        src = edge + (size_t)(b0 + row) * 1024 + a * 128 + (ks - 4) * 32 + c8 * 8;
      float4 v0 = *(const float4*)src;
      float4 v1 = *(const float4*)(src + 4);
      *(short8*)&As[row * LDA + c8 * 8] = cvt8(v0, v1);
    }
    // --- stage B (already bf16): 128x32, 16 shorts/thread ---
#pragma unroll
    for (int i = 0; i < 2; ++i) {
      int chunk = tid + i * 256;
      int row = chunk >> 2, c = chunk & 3;
      *(short8*)&Bs[row * LDA + c * 8] =
          *(const short8*)(Mta + row * 256 + ks * 32 + c * 8);
    }
    __syncthreads();

    short8 af[4], bfr[4];
#pragma unroll
    for (int mt = 0; mt < 4; ++mt)  // A frag: A[m=l16][k=quad*8+j]
      af[mt] = *(const short8*)&As[(wm * 64 + mt * 16 + l16) * LDA + quad * 8];
#pragma unroll
    for (int nt = 0; nt < 4; ++nt)  // B frag: B[k=quad*8+j][n=l16] via Bs[n][k]
      bfr[nt] = *(const short8*)&Bs[(wn * 64 + nt * 16 + l16) * LDA + quad * 8];
#pragma unroll
    for (int mt = 0; mt < 4; ++mt)
#pragma unroll
      for (int nt = 0; nt < 4; ++nt)
        acc[mt][nt] = __builtin_amdgcn_mfma_f32_16x16x32_bf16(
            af[mt], bfr[nt], acc[mt][nt], 0, 0, 0);
    __syncthreads();
  }

  // --- epilogue: C/D layout col=lane&15, row=quad*4+reg ---
  float bias[4];
#pragma unroll
  for (int nt = 0; nt < 4; ++nt)
    bias[nt] = bias2[a * 128 + wn * 64 + nt * 16 + l16];
#pragma unroll
  for (int mt = 0; mt < 4; ++mt)
#pragma unroll
    for (int nt = 0; nt < 4; ++nt) {
      int j = wn * 64 + nt * 16 + l16;
#pragma unroll
      for (int r = 0; r < 4; ++r) {
        int b = b0 + wm * 64 + mt * 16 + quad * 4 + r;
        out[(size_t)b * 1024 + a * 128 + j] = acc[mt][nt][r] + bias[nt];
      }
    }
}

extern "C" void kernel_launch(void* const* d_in, const int* in_sizes, int n_in,
                              void* d_out, int out_size, void* d_ws,
                              size_t ws_size, hipStream_t stream) {
  const float* img  = (const float*)d_in[0];  // [65536,128]
  const float* edge = (const float*)d_in[1];  // [65536,8,128]
  const float* W    = (const float*)d_in[2];  // [128,256]
  const float* bv   = (const float*)d_in[3];  // [128]
  const float* proj = (const float*)d_in[4];  // [8,128,128]
  float* out = (float*)d_out;                 // [65536,8,128]

  short* Mt = (short*)d_ws;                         // 8*128*256 bf16 = 512 KB
  float* bias2 = (float*)((char*)d_ws + 8 * 128 * 256 * 2);  // 4 KB

  prep_M<<<1024, 256, 0, stream>>>(W, proj, bv, Mt, bias2);
  gemm_main<<<4096, 256, 0, stream>>>(img, edge, Mt, bias2, out);
}